// Round 4
// baseline (314.069 us; speedup 1.0000x reference)
//
#include <hip/hip_runtime.h>
#include <hip/hip_bf16.h>
#include <stdint.h>

#define IN_FEATS 128
#define OUT_FEATS 256
#define TOPK 32
#define BM 128
#define BN 128
#define BK 32
#define KTOT 256

typedef float f32x4 __attribute__((ext_vector_type(4)));
typedef short bf16x8 __attribute__((ext_vector_type(8)));

__device__ __forceinline__ unsigned short f2bf(float x) {
    unsigned u = __float_as_uint(x);
    u += 0x7FFFu + ((u >> 16) & 1u);   // round-to-nearest-even
    return (unsigned short)(u >> 16);
}

// async global->LDS 16B per lane: LDS dest = wave-uniform base + lane*16
__device__ __forceinline__ void async16(const void* g, void* l) {
    __builtin_amdgcn_global_load_lds(
        (const __attribute__((address_space(1))) unsigned*)g,
        (__attribute__((address_space(3))) unsigned*)l, 16, 0, 0);
}

// K1: scatter top-k (values,indices) into dense bf16 x_sparse [N,128].
// Duplicate indices must ACCUMULATE (reference uses .add) -> atomicAdd in LDS.
__global__ void k_scatter(const float* __restrict__ vals, const int* __restrict__ idxs,
                          unsigned short* __restrict__ xsp, int n_nodes) {
    __shared__ float lds[2 * IN_FEATS];
    int t = threadIdx.x;
    int n0 = blockIdx.x * 2;
    lds[t] = 0.f;
    __syncthreads();
    if (t < 2 * TOPK) {
        int h = t >> 5;          // which of the 2 nodes
        int k = t & 31;
        int n = n0 + h;
        if (n < n_nodes) {
            float v = vals[(size_t)n * TOPK + k];
            int ix = idxs[(size_t)n * TOPK + k];
            atomicAdd(&lds[h * IN_FEATS + ix], v);
        }
    }
    __syncthreads();
    int h2 = t >> 7;
    int f = t & 127;
    int n = n0 + h2;
    if (n < n_nodes) xsp[(size_t)n * IN_FEATS + f] = f2bf(lds[t]);
}

// Kw: build W^T bf16 [256 outs][256 ks], rows = output col, concat K = [W_neigh; W_self]
__global__ void k_weights(const float* __restrict__ Wn, const float* __restrict__ Ws,
                          unsigned short* __restrict__ WT) {
    int idx = blockIdx.x * 256 + threadIdx.x;   // 0..65535
    int n = idx >> 8;
    int k = idx & 255;
    float v = (k < IN_FEATS) ? Wn[(size_t)k * OUT_FEATS + n]
                             : Ws[(size_t)(k - IN_FEATS) * OUT_FEATS + n];
    WT[idx] = f2bf(v);
}

// Ki: build indptr[N+1] from sorted row[] (edge-parallel, writes gap ranges).
__global__ void k_indptr(const int* __restrict__ row, int* __restrict__ indptr,
                         int n_nodes, int n_edges) {
    int e = blockIdx.x * 256 + threadIdx.x;
    if (e >= n_edges) return;
    int r = row[e];
    int rp = (e == 0) ? -1 : row[e - 1];
    for (int x = rp + 1; x <= r; ++x) indptr[x] = e;
    if (e == n_edges - 1)
        for (int x = r + 1; x <= n_nodes; ++x) indptr[x] = n_edges;
}

// K2: mean aggregation + fused feat f32->bf16 cast.
// One wave per node; lane = eg*16 + fi: 16 lanes x 16B cover one bf16 row,
// 4 edges per wave-load, unrolled x2 -> 8 gathers in flight.
// Writes into Acat[node][0..127] (agg) and Acat[node][128..255] (feat bf16).
__global__ __launch_bounds__(256) void k_aggregate(
    const unsigned short* __restrict__ xsp,
    const float* __restrict__ feat,
    const int* __restrict__ indptr, const int* __restrict__ col,
    unsigned short* __restrict__ Acat, int n_nodes) {
    int t = threadIdx.x;
    int node = blockIdx.x * 4 + (t >> 6);
    if (node >= n_nodes) return;
    int lane = t & 63;
    int eg = lane >> 4, fi = lane & 15;
    int e0 = indptr[node], e1 = indptr[node + 1];

    // fused featcast: issue early, independent of edge loop
    float2 fv = *(const float2*)(feat + (size_t)node * IN_FEATS + lane * 2);

    float acc[8] = {0.f, 0.f, 0.f, 0.f, 0.f, 0.f, 0.f, 0.f};
    int elast = (e1 > e0) ? (e1 - 1) : e0;
    for (int base = e0; base < e1; base += 8) {
        int ea = base + eg;
        int eb = base + 4 + eg;
        float sa = (ea < e1) ? 1.f : 0.f;
        float sb = (eb < e1) ? 1.f : 0.f;
        int ca = col[ea < elast ? ea : elast];
        int cb = col[eb < elast ? eb : elast];
        uint4 ua = *(const uint4*)(xsp + (size_t)ca * IN_FEATS + fi * 8);
        uint4 ub = *(const uint4*)(xsp + (size_t)cb * IN_FEATS + fi * 8);
        unsigned pa[4] = {ua.x, ua.y, ua.z, ua.w};
        unsigned pb[4] = {ub.x, ub.y, ub.z, ub.w};
#pragma unroll
        for (int i = 0; i < 4; ++i) {
            acc[2 * i]     = fmaf(sa, __uint_as_float(pa[i] << 16), acc[2 * i]);
            acc[2 * i + 1] = fmaf(sa, __uint_as_float(pa[i] & 0xFFFF0000u), acc[2 * i + 1]);
            acc[2 * i]     = fmaf(sb, __uint_as_float(pb[i] << 16), acc[2 * i]);
            acc[2 * i + 1] = fmaf(sb, __uint_as_float(pb[i] & 0xFFFF0000u), acc[2 * i + 1]);
        }
    }
    unsigned pk = (unsigned)f2bf(fv.x) | ((unsigned)f2bf(fv.y) << 16);
    *(unsigned*)(Acat + (size_t)node * KTOT + IN_FEATS + lane * 2) = pk;

    // reduce across the 4 edge subgroups (stride 16, 32)
#pragma unroll
    for (int i = 0; i < 8; ++i) {
        acc[i] += __shfl_down(acc[i], 16, 64);
        acc[i] += __shfl_down(acc[i], 32, 64);
    }
    if (eg == 0) {
        int cnt = e1 - e0;
        float inv = 1.0f / (float)(cnt > 0 ? cnt : 1);  // == 1/max(deg,1)
        unsigned o[4];
#pragma unroll
        for (int i = 0; i < 4; ++i) {
            unsigned lo = f2bf(acc[2 * i] * inv);
            unsigned hi = f2bf(acc[2 * i + 1] * inv);
            o[i] = lo | (hi << 16);
        }
        *(uint4*)(Acat + (size_t)node * KTOT + fi * 8) = *(uint4*)&o[0];
    }
}

// K3: rst = Acat @ Wcat^T + bias.  M=n_nodes, K=256, N=256.
// 128x128 tile, 4 waves, 4x4 grid of 16x16x32 bf16 MFMAs per wave.
// Staging via global_load_lds (16B/lane, per-lane global gather):
// lane = g*16 + r lands LDS layout [seg][kgrp g][row r][16B] -> fragment
// reads are uniform 8-accesses/bank (structural minimum for b128).
__global__ __launch_bounds__(256) void k_gemm(
    const unsigned short* __restrict__ Acat,  // [N,256] bf16
    const unsigned short* __restrict__ WT,    // [256][256] bf16, WT[n][k]
    const float* __restrict__ bias,
    float* __restrict__ out, int n_nodes) {
    __shared__ __align__(16) unsigned short Ash[BM * BK];  // 8 KB
    __shared__ __align__(16) unsigned short Bsh[BN * BK];  // 8 KB
    int t = threadIdx.x;
    int m0 = blockIdx.x * BM;
    int n0 = blockIdx.y * BN;
    int lane = t & 63;
    int w = t >> 6;
    int wr = w >> 1, wc = w & 1;
    int lrow = lane & 15, quad = lane >> 4;
    int g = lane >> 4, r = lane & 15;   // staging decomposition

    f32x4 acc[4][4];
    for (int i = 0; i < 4; ++i)
        for (int j = 0; j < 4; ++j)
            acc[i][j] = (f32x4){0.f, 0.f, 0.f, 0.f};

    for (int kk = 0; kk < KTOT; kk += BK) {
#pragma unroll
        for (int p = 0; p < 2; ++p) {
            int seg = 2 * w + p;                 // wave-uniform
            int arow = m0 + seg * 16 + r;
            if (arow > n_nodes - 1) arow = n_nodes - 1;
            async16(Acat + (size_t)arow * KTOT + kk + g * 8, &Ash[seg * 512]);
            int brow = n0 + seg * 16 + r;
            async16(WT + (size_t)brow * KTOT + kk + g * 8, &Bsh[seg * 512]);
        }
        __syncthreads();   // drains vmcnt -> DMA complete

        bf16x8 af[4], bfr[4];
#pragma unroll
        for (int mi = 0; mi < 4; ++mi)
            af[mi] = *(const bf16x8*)&Ash[(wr * 4 + mi) * 512 + quad * 128 + lrow * 8];
#pragma unroll
        for (int ni = 0; ni < 4; ++ni)
            bfr[ni] = *(const bf16x8*)&Bsh[(wc * 4 + ni) * 512 + quad * 128 + lrow * 8];
#pragma unroll
        for (int mi = 0; mi < 4; ++mi)
#pragma unroll
            for (int ni = 0; ni < 4; ++ni)
                acc[mi][ni] = __builtin_amdgcn_mfma_f32_16x16x32_bf16(
                    af[mi], bfr[ni], acc[mi][ni], 0, 0, 0);
        __syncthreads();
    }

    // epilogue: C/D layout col=lane&15, row=quad*4+reg
    for (int mi = 0; mi < 4; ++mi) {
        int gm = m0 + wr * 64 + mi * 16 + quad * 4;
        for (int ni = 0; ni < 4; ++ni) {
            int go = n0 + wc * 64 + ni * 16 + lrow;
            float b = bias[go];
            for (int rr = 0; rr < 4; ++rr) {
                int node = gm + rr;
                if (node < n_nodes)
                    out[(size_t)node * OUT_FEATS + go] = acc[mi][ni][rr] + b;
            }
        }
    }
}

extern "C" void kernel_launch(void* const* d_in, const int* in_sizes, int n_in,
                              void* d_out, int out_size, void* d_ws, size_t ws_size,
                              hipStream_t stream) {
    const float* feat = (const float*)d_in[0];
    const float* tkv  = (const float*)d_in[1];
    const int*   tki  = (const int*)d_in[2];
    const int*   row  = (const int*)d_in[3];
    const int*   col  = (const int*)d_in[4];
    const float* Wn   = (const float*)d_in[6];
    const float* Ws   = (const float*)d_in[7];
    const float* bias = (const float*)d_in[8];
    float* out = (float*)d_out;

    int n_nodes = in_sizes[5];
    int n_edges = in_sizes[3];

    // ws: x_sparse bf16 [N,128] | Acat bf16 [N,256] | WT bf16 [256,256] | indptr [N+1]
    unsigned short* xsp  = (unsigned short*)d_ws;
    unsigned short* Acat = xsp + (size_t)n_nodes * IN_FEATS;
    unsigned short* WT   = Acat + (size_t)n_nodes * KTOT;
    int* indptr = (int*)(WT + (size_t)OUT_FEATS * KTOT);

    k_scatter<<<(n_nodes + 1) / 2, 256, 0, stream>>>(tkv, tki, xsp, n_nodes);
    k_weights<<<256, 256, 0, stream>>>(Wn, Ws, WT);
    k_indptr<<<(n_edges + 255) / 256, 256, 0, stream>>>(row, indptr, n_nodes, n_edges);
    k_aggregate<<<(n_nodes + 3) / 4, 256, 0, stream>>>(xsp, feat, indptr, col, Acat, n_nodes);
    dim3 g3((n_nodes + BM - 1) / BM, OUT_FEATS / BN);
    k_gemm<<<g3, 256, 0, stream>>>(Acat, WT, bias, out, n_nodes);
}